// Round 9
// baseline (331.127 us; speedup 1.0000x reference)
//
#include <hip/hip_runtime.h>
#include <math.h>

typedef unsigned int uint32;
typedef __attribute__((ext_vector_type(8))) short bf16x8;
typedef __attribute__((ext_vector_type(4))) float f32x4;

__device__ __forceinline__ ushort f2bf(float f) {
  uint32 u = __builtin_bit_cast(uint32, f);
  uint32 r = (u + 0x7fff + ((u >> 16) & 1)) >> 16;  // RNE
  return (ushort)r;
}
__device__ __forceinline__ float bf_lo(uint32 u) {
  return __builtin_bit_cast(float, u << 16);
}
__device__ __forceinline__ float bf_hi(uint32 u) {
  return __builtin_bit_cast(float, u & 0xffff0000u);
}

#define NBBITS 8
#define BKNODES 256
#define CH 4096
#define NBMAX 512

// ---------------------------------------------------------------------------
// prep: convert W_fc/W_dst to bf16 (global, L1-resident in gemm) + zero the
// bucket counters. Replaces the hipMemsetAsync dispatch.
// ---------------------------------------------------------------------------
__global__ __launch_bounds__(256) void prep(const float* __restrict__ W_fc,
                                            const float* __restrict__ W_dst,
                                            ushort* __restrict__ Wb_fc,
                                            ushort* __restrict__ Wb_dst,
                                            int* __restrict__ zeroBuf, int nZero) {
  const int tid = blockIdx.x * 256 + threadIdx.x;
  const int stride = gridDim.x * 256;
  for (int i = tid; i < (64 * 256) / 4; i += stride) {
    float4 v = ((const float4*)W_fc)[i];
    ushort4 b;
    b.x = f2bf(v.x); b.y = f2bf(v.y); b.z = f2bf(v.z); b.w = f2bf(v.w);
    ((ushort4*)Wb_fc)[i] = b;
  }
  for (int i = tid; i < (64 * 64) / 4; i += stride) {
    float4 v = ((const float4*)W_dst)[i];
    ushort4 b;
    b.x = f2bf(v.x); b.y = f2bf(v.y); b.z = f2bf(v.z); b.w = f2bf(v.w);
    ((ushort4*)Wb_dst)[i] = b;
  }
  for (int i = tid; i < nZero; i += stride) zeroBuf[i] = 0;
}

// ---------------------------------------------------------------------------
// LDS-free GEMM: A frags global->reg (depth-1 prefetch), B frags read
// directly from pre-converted bf16 W in global (32 KB, L1-resident).
// No LDS, no barriers -> occupancy VGPR-bound (~20+ waves/CU vs 10 w/ LDS).
// ---------------------------------------------------------------------------
template <int K, bool BF16OUT>
__device__ __forceinline__ void gemm_body(const float* __restrict__ A,
                                          const ushort* __restrict__ Wb,
                                          ushort* __restrict__ Cb,
                                          float* __restrict__ C,
                                          int M, int bx) {
  const int t = threadIdx.x;
  const int lane = t & 63;
  const int w = t >> 6;
  const int quad = lane >> 4;
  const int l16 = lane & 15;
  const int rBase = bx * 128;

  f32x4 acc[2][4];
  #pragma unroll
  for (int i = 0; i < 2; ++i)
    #pragma unroll
    for (int n = 0; n < 4; ++n) acc[i][n] = (f32x4){0.f, 0.f, 0.f, 0.f};

  const int r0 = min(rBase + w * 32 + l16, M - 1);
  const int r1 = min(rBase + w * 32 + 16 + l16, M - 1);
  const float* __restrict__ a0 = A + (size_t)r0 * K + quad * 8;
  const float* __restrict__ a1 = A + (size_t)r1 * K + quad * 8;

  float4 c00 = *(const float4*)(a0);
  float4 c01 = *(const float4*)(a0 + 4);
  float4 c10 = *(const float4*)(a1);
  float4 c11 = *(const float4*)(a1 + 4);

  #pragma unroll 2
  for (int kb = 0; kb < K; kb += 32) {
    float4 n00, n01, n10, n11;
    const bool more = (kb + 32 < K);
    if (more) {
      n00 = *(const float4*)(a0 + kb + 32);
      n01 = *(const float4*)(a0 + kb + 36);
      n10 = *(const float4*)(a1 + kb + 32);
      n11 = *(const float4*)(a1 + kb + 36);
    }

    bf16x8 af0, af1;
    af0[0] = (short)f2bf(c00.x); af0[1] = (short)f2bf(c00.y);
    af0[2] = (short)f2bf(c00.z); af0[3] = (short)f2bf(c00.w);
    af0[4] = (short)f2bf(c01.x); af0[5] = (short)f2bf(c01.y);
    af0[6] = (short)f2bf(c01.z); af0[7] = (short)f2bf(c01.w);
    af1[0] = (short)f2bf(c10.x); af1[1] = (short)f2bf(c10.y);
    af1[2] = (short)f2bf(c10.z); af1[3] = (short)f2bf(c10.w);
    af1[4] = (short)f2bf(c11.x); af1[5] = (short)f2bf(c11.y);
    af1[6] = (short)f2bf(c11.z); af1[7] = (short)f2bf(c11.w);

    bf16x8 bfrag[4];
    #pragma unroll
    for (int n = 0; n < 4; ++n)
      bfrag[n] = *(const bf16x8*)(Wb + (size_t)(n * 16 + l16) * K + kb + quad * 8);

    #pragma unroll
    for (int n = 0; n < 4; ++n) {
      acc[0][n] = __builtin_amdgcn_mfma_f32_16x16x32_bf16(af0, bfrag[n], acc[0][n], 0, 0, 0);
      acc[1][n] = __builtin_amdgcn_mfma_f32_16x16x32_bf16(af1, bfrag[n], acc[1][n], 0, 0, 0);
    }

    if (more) { c00 = n00; c01 = n01; c10 = n10; c11 = n11; }
  }

  #pragma unroll
  for (int i = 0; i < 2; ++i)
    #pragma unroll
    for (int nt = 0; nt < 4; ++nt)
      #pragma unroll
      for (int r = 0; r < 4; ++r) {
        int row = rBase + w * 32 + i * 16 + quad * 4 + r;
        int col = nt * 16 + l16;
        if (row < M) {
          if (BF16OUT)
            Cb[(size_t)row * 64 + col] = f2bf(acc[i][nt][r]);
          else
            C[(size_t)row * 64 + col] = acc[i][nt][r];
        }
      }
}

__device__ __forceinline__ void count_body(const int* __restrict__ dst,
                                           int* __restrict__ bCnt,
                                           int E, int NB, int cb, int* lcnt) {
  const int t = threadIdx.x;
  for (int i = t; i < NB; i += 256) lcnt[i] = 0;
  __syncthreads();
  const int c0 = cb * CH, c1 = min(c0 + CH, E);
  for (int i = c0 + t; i < c1; i += 256) atomicAdd(&lcnt[dst[i] >> NBBITS], 1);
  __syncthreads();
  for (int b = t; b < NB; b += 256) {
    int c = lcnt[b];
    if (c) atomicAdd(&bCnt[b], c);
  }
}

// Fused: blocks [0,nChunks) do csr_count (dispatched first -> overlap with
// gemm); then 256-K gemm blocks; then 64-K gemm blocks. LDS = 2 KB only.
__global__ __launch_bounds__(256, 4) void gemm_count(const float* __restrict__ h,
                                                     const float* __restrict__ feat,
                                                     const ushort* __restrict__ Wb_fc,
                                                     const ushort* __restrict__ Wb_dst,
                                                     ushort* __restrict__ zb,
                                                     float* __restrict__ df,
                                                     const int* __restrict__ dst,
                                                     int* __restrict__ bCnt,
                                                     int M, int gsplit, int E, int NB,
                                                     int nChunks) {
  __shared__ int lcnt[NBMAX];
  const int bx = (int)blockIdx.x;
  if (bx < nChunks)
    count_body(dst, bCnt, E, NB, bx, lcnt);
  else if (bx < nChunks + gsplit)
    gemm_body<256, true>(h, Wb_fc, zb, nullptr, M, bx - nChunks);
  else
    gemm_body<64, false>(feat, Wb_dst, nullptr, df, M, bx - nChunks - gsplit);
}

// ---------------------------------------------------------------------------
// 512-thread CSR kernels (8 waves/block -> 2x the latency-hiding width).
// ---------------------------------------------------------------------------
__device__ __forceinline__ void scan512w(const int* __restrict__ bCnt, int NB,
                                         int* sc) {
  const int t = threadIdx.x;  // 0..511
  sc[t] = (t < NB) ? bCnt[t] : 0;
  __syncthreads();
  for (int off = 1; off < NBMAX; off <<= 1) {
    int v = sc[t];
    int a = (t >= off) ? sc[t - off] : 0;
    __syncthreads();
    sc[t] = v + a;
    __syncthreads();
  }
}

__global__ __launch_bounds__(512) void csr_partition(const int* __restrict__ src,
                                                     const int* __restrict__ dst,
                                                     const int* __restrict__ bCnt,
                                                     int* __restrict__ relCur,
                                                     unsigned* __restrict__ packed,
                                                     int E, int NB) {
  __shared__ int sc[NBMAX];
  __shared__ int lcnt[NBMAX];
  __shared__ int lbase[NBMAX];
  const int t = threadIdx.x;
  scan512w(bCnt, NB, sc);  // inclusive scan
  lcnt[t] = 0;
  __syncthreads();
  const int c0 = blockIdx.x * CH, c1 = min(c0 + CH, E);
  for (int i = c0 + t; i < c1; i += 512) atomicAdd(&lcnt[dst[i] >> NBBITS], 1);
  __syncthreads();
  if (t < NB) {
    int c = lcnt[t];
    lbase[t] = c ? (sc[t] - bCnt[t] + atomicAdd(&relCur[t], c)) : 0;
  }
  __syncthreads();
  for (int i = c0 + t; i < c1; i += 512) {
    int dv = dst[i];
    int b = dv >> NBBITS;
    int pos = atomicAdd(&lbase[b], 1);
    packed[pos] = ((unsigned)src[i] << NBBITS) | (unsigned)(dv & (BKNODES - 1));
  }
}

__global__ __launch_bounds__(512) void csr_finalize(const int* __restrict__ bCnt,
                                                    const unsigned* __restrict__ packed,
                                                    int* __restrict__ edgeSrc,
                                                    int* __restrict__ offsets,
                                                    int N, int NB, int E) {
  __shared__ int sc[NBMAX];
  __shared__ int sh[BKNODES];
  const int r = blockIdx.x;
  const int t = threadIdx.x;
  scan512w(bCnt, NB, sc);
  const int endr = sc[r];
  const int base = endr - bCnt[r];
  if (t < BKNODES) sh[t] = 0;
  __syncthreads();
  for (int i = base + t; i < endr; i += 512)
    atomicAdd(&sh[packed[i] & (BKNODES - 1)], 1);
  __syncthreads();
  const int cnt_t = (t < BKNODES) ? sh[t] : 0;
  // inclusive scan over the 256 node counts (512 threads, 256 active)
  for (int off = 1; off < BKNODES; off <<= 1) {
    int v = 0;
    if (t < BKNODES) v = sh[t] + ((t >= off) ? sh[t - off] : 0);
    __syncthreads();
    if (t < BKNODES) sh[t] = v;
    __syncthreads();
  }
  if (t < BKNODES) sh[t] = base + sh[t] - cnt_t;  // base + exclusive prefix
  __syncthreads();
  const int node0 = r << NBBITS;
  if (t < BKNODES) {
    int g = node0 + t;
    if (g < N) offsets[g] = sh[t];
  }
  if (r == NB - 1 && t == 0) offsets[N] = E;
  __syncthreads();
  for (int i = base + t; i < endr; i += 512) {
    unsigned v = packed[i];
    int pos = atomicAdd(&sh[v & (BKNODES - 1)], 1);
    edgeSrc[pos] = (int)(v >> NBBITS);
  }
}

// ---------------------------------------------------------------------------
// Grid-stride persistent-wave aggregate (unchanged, measured ~70 us).
// ---------------------------------------------------------------------------
__global__ __launch_bounds__(256) void aggregate(const ushort* __restrict__ zb,
                                                 const float* __restrict__ df,
                                                 const int* __restrict__ offsets,
                                                 const int* __restrict__ edgeSrc,
                                                 float* __restrict__ out, int N, int NW) {
  const int lane = threadIdx.x & 63;
  int d = __builtin_amdgcn_readfirstlane((int)((blockIdx.x * blockDim.x + threadIdx.x) >> 6));
  if (d >= N) return;
  const int g = lane >> 4;
  const int l16 = lane & 15;

  int beg = offsets[d];
  int end = offsets[d + 1];
  float4 df4 = *(const float4*)(df + (size_t)d * 64 + l16 * 4);

  while (true) {
    const int nd = d + NW;
    const int ndc = min(nd, N - 1);
    const int nbeg = offsets[ndc];
    const int nend = offsets[ndc + 1];
    const float4 ndf4 = *(const float4*)(df + (size_t)ndc * 64 + l16 * 4);

    float m = -INFINITY, l = 0.f;
    float ax = 0.f, ay = 0.f, az = 0.f, aw = 0.f;

    for (int j0 = beg; j0 < end; j0 += 32) {
      const int nst = min(8, (end - j0 + 3) >> 2);
      uint2 zf[8];
      float ew[8];
      float bm = -INFINITY;

      #pragma unroll
      for (int st = 0; st < 8; ++st) {
        if (st < nst) {
          const int eidx = j0 + st * 4 + g;
          const bool act = eidx < end;
          int s = 0;
          if (act) s = edgeSrc[eidx];
          zf[st] = *(const uint2*)(zb + (size_t)s * 64 + l16 * 4);
          float p = bf_lo(zf[st].x) * df4.x;
          p = fmaf(bf_hi(zf[st].x), df4.y, p);
          p = fmaf(bf_lo(zf[st].y), df4.z, p);
          p = fmaf(bf_hi(zf[st].y), df4.w, p);
          p += __shfl_xor(p, 1, 64);
          p += __shfl_xor(p, 2, 64);
          p += __shfl_xor(p, 4, 64);
          p += __shfl_xor(p, 8, 64);
          ew[st] = act ? p : -INFINITY;
          bm = fmaxf(bm, ew[st]);
        }
      }
      bm = fmaxf(bm, __shfl_xor(bm, 16, 64));
      bm = fmaxf(bm, __shfl_xor(bm, 32, 64));

      const float nm = fmaxf(m, bm);
      const float alpha = __expf(m - nm);
      float sw = 0.f;
      #pragma unroll
      for (int st = 0; st < 8; ++st) {
        if (st < nst) {
          const float w = __expf(ew[st] - nm);
          ew[st] = w;
          sw += w;
        }
      }
      sw += __shfl_xor(sw, 16, 64);
      sw += __shfl_xor(sw, 32, 64);
      l = l * alpha + sw;
      m = nm;

      ax *= alpha; ay *= alpha; az *= alpha; aw *= alpha;
      #pragma unroll
      for (int st = 0; st < 8; ++st) {
        if (st < nst) {
          const float w = ew[st];
          ax = fmaf(w, bf_lo(zf[st].x), ax);
          ay = fmaf(w, bf_hi(zf[st].x), ay);
          az = fmaf(w, bf_lo(zf[st].y), az);
          aw = fmaf(w, bf_hi(zf[st].y), aw);
        }
      }
    }

    ax += __shfl_xor(ax, 16, 64); ax += __shfl_xor(ax, 32, 64);
    ay += __shfl_xor(ay, 16, 64); ay += __shfl_xor(ay, 32, 64);
    az += __shfl_xor(az, 16, 64); az += __shfl_xor(az, 32, 64);
    aw += __shfl_xor(aw, 16, 64); aw += __shfl_xor(aw, 32, 64);

    if (lane < 16) {
      const float inv = (l > 0.f) ? (1.f / l) : 0.f;
      float4 o;
      o.x = ax * inv; o.y = ay * inv; o.z = az * inv; o.w = aw * inv;
      *(float4*)(out + (size_t)d * 64 + l16 * 4) = o;
    }

    if (nd >= N) break;
    d = nd; beg = nbeg; end = nend; df4 = ndf4;
  }
}

// ---------------------------------------------------------------------------
extern "C" void kernel_launch(void* const* d_in, const int* in_sizes, int n_in,
                              void* d_out, int out_size, void* d_ws, size_t ws_size,
                              hipStream_t stream) {
  const float* h     = (const float*)d_in[0];  // [N,256]
  const float* feat  = (const float*)d_in[1];  // [N,64]
  const float* W_fc  = (const float*)d_in[2];  // [64,256]
  const float* W_dst = (const float*)d_in[3];  // [64,64]
  const int*   src   = (const int*)d_in[4];    // [E]
  const int*   dst   = (const int*)d_in[5];    // [E]
  float* out = (float*)d_out;

  const int N = in_sizes[1] / 64;        // 100000
  const int E = in_sizes[4];             // 1600000

  const int NB = (N + BKNODES - 1) >> NBBITS;  // 391 buckets
  const int nChunks = (E + CH - 1) / CH;       // 391

  // workspace layout (Wb first for 16-B alignment)
  char* ws = (char*)d_ws;
  ushort* Wb_fc = (ushort*)ws;                     // 64*256 bf16
  ushort* Wb_dst = Wb_fc + 64 * 256;               // 64*64 bf16
  ushort* zb = Wb_dst + 64 * 64;                   // N*64 bf16
  float* df = (float*)(zb + (size_t)N * 64);       // N*64 f32
  int* offsets = (int*)(df + (size_t)N * 64);      // N+1
  int* edgeSrc = offsets + N + 1;                  // E
  int* bCnt = edgeSrc + E;                         // NB
  int* relCur = bCnt + NB;                         // NB (contiguous with bCnt)
  // packed scratch lives in d_out (E u32 <= N*64 f32), consumed before aggregate
  unsigned* packed = (unsigned*)d_out;

  prep<<<32, 256, 0, stream>>>(W_fc, W_dst, Wb_fc, Wb_dst, bCnt, 2 * NB);

  const int gsplit = (N + 127) / 128;  // 782
  gemm_count<<<nChunks + gsplit * 2, 256, 0, stream>>>(h, feat, Wb_fc, Wb_dst, zb, df,
                                                       dst, bCnt, N, gsplit, E, NB,
                                                       nChunks);

  csr_partition<<<nChunks, 512, 0, stream>>>(src, dst, bCnt, relCur, packed, E, NB);
  csr_finalize<<<NB, 512, 0, stream>>>(bCnt, packed, edgeSrc, offsets, N, NB, E);

  // persistent-wave aggregate: 2048 blocks x 4 waves = 8192 waves
  const int aggBlocks = 2048;
  const int NW = aggBlocks * 4;
  aggregate<<<aggBlocks, 256, 0, stream>>>(zb, df, offsets, edgeSrc, out, N, NW);
}